// Round 1
// baseline (11345.267 us; speedup 1.0000x reference)
//
#include <hip/hip_runtime.h>

#define D 256  // D_IN == D_OUT == 256

// ---------------------------------------------------------------------------
// Kernel 1: support = x @ W   (fp32, vector ALU — no fp32 MFMA on CDNA4)
// One wave per output row. x-row staged in LDS (broadcast reads, no bank
// conflict: same address). Each lane accumulates 4 consecutive outputs via
// float4 loads of W rows (W = 256 KB -> L2-resident, heavy L1 reuse).
// ---------------------------------------------------------------------------
__global__ __launch_bounds__(256) void gemm_xw(const float* __restrict__ x,
                                               const float* __restrict__ w,
                                               float* __restrict__ support,
                                               int N) {
    __shared__ float xrow[4][D];
    const int wave = threadIdx.x >> 6;
    const int lane = threadIdx.x & 63;
    const int row  = blockIdx.x * 4 + wave;
    const int r    = row < N ? row : N - 1;  // clamp so __syncthreads stays uniform

    float4 xv = *(const float4*)(x + (size_t)r * D + lane * 4);
    *(float4*)(&xrow[wave][lane * 4]) = xv;
    __syncthreads();

    float4 acc = make_float4(0.f, 0.f, 0.f, 0.f);
#pragma unroll 8
    for (int k = 0; k < D; ++k) {
        const float  xk = xrow[wave][k];
        const float4 wv = *(const float4*)(w + k * D + lane * 4);
        acc.x = fmaf(xk, wv.x, acc.x);
        acc.y = fmaf(xk, wv.y, acc.y);
        acc.z = fmaf(xk, wv.z, acc.z);
        acc.w = fmaf(xk, wv.w, acc.w);
    }
    if (row < N) *(float4*)(support + (size_t)row * D + lane * 4) = acc;
}

// ---------------------------------------------------------------------------
// Kernel 2: out[i][:] = bias[:]   (harness poisons d_out once; we must fully
// re-initialize every call since atomics accumulate on top)
// ---------------------------------------------------------------------------
__global__ __launch_bounds__(256) void init_out(float* __restrict__ out,
                                                const float* __restrict__ bias,
                                                int N) {
    const int idx   = blockIdx.x * blockDim.x + threadIdx.x;  // one float4 each
    const int total = N * (D / 4);
    if (idx >= total) return;
    const int d4 = idx & (D / 4 - 1);
    const float4 b = *(const float4*)(bias + d4 * 4);
    *(float4*)(out + (size_t)idx * 4) = b;
}

// ---------------------------------------------------------------------------
// Kernel 3: edge scatter. One wave per edge; lane handles 4 consecutive dims.
// support gather is random-row but L3-resident (102 MB < 256 MB Infinity
// Cache). Output accumulation via device-scope f32 atomics.
// ---------------------------------------------------------------------------
__global__ __launch_bounds__(256) void scatter_edges(const float* __restrict__ support,
                                                     const float* __restrict__ edge_val,
                                                     const int* __restrict__ edge_row,
                                                     const int* __restrict__ edge_col,
                                                     float* __restrict__ out,
                                                     int E) {
    const int e = blockIdx.x * 4 + (threadIdx.x >> 6);
    if (e >= E) return;
    const int lane = threadIdx.x & 63;

    const int   row = edge_row[e];
    const int   col = edge_col[e];
    const float v   = edge_val[e];

    const float4 sv = *(const float4*)(support + (size_t)col * D + lane * 4);
    float* o = out + (size_t)row * D + lane * 4;
    atomicAdd(o + 0, v * sv.x);
    atomicAdd(o + 1, v * sv.y);
    atomicAdd(o + 2, v * sv.z);
    atomicAdd(o + 3, v * sv.w);
}

// ---------------------------------------------------------------------------
extern "C" void kernel_launch(void* const* d_in, const int* in_sizes, int n_in,
                              void* d_out, int out_size, void* d_ws, size_t ws_size,
                              hipStream_t stream) {
    const float* x        = (const float*)d_in[0];
    const float* edge_val = (const float*)d_in[1];
    const float* weight   = (const float*)d_in[2];
    const float* bias     = (const float*)d_in[3];
    const int*   edge_row = (const int*)d_in[4];
    const int*   edge_col = (const int*)d_in[5];
    float*       out      = (float*)d_out;

    const int N = in_sizes[0] / D;   // 100000
    const int E = in_sizes[1];       // 3200000

    float* support = (float*)d_ws;   // N*D*4 = 102.4 MB scratch

    // 1) support = x @ W
    gemm_xw<<<(N + 3) / 4, 256, 0, stream>>>(x, weight, support, N);

    // 2) out = bias (broadcast)
    init_out<<<(N * (D / 4) + 255) / 256, 256, 0, stream>>>(out, bias, N);

    // 3) out[row] += val * support[col] over all edges
    scatter_edges<<<(E + 3) / 4, 256, 0, stream>>>(support, edge_val, edge_row,
                                                   edge_col, out, E);
}

// Round 2
// 970.005 us; speedup vs baseline: 11.6961x; 11.6961x over previous
//
#include <hip/hip_runtime.h>

#define D 256  // D_IN == D_OUT == 256

// ===========================================================================
// Kernel 1: support = x @ W  (fp32 vector ALU; no fp32 MFMA on CDNA4)
// 4 waves/block, 8 rows/wave -> 32 rows/block staged in LDS (32 KB).
// W row loads amortized 8x vs 1-row-per-wave (L2 traffic 25.6 GB -> 3.2 GB).
// ===========================================================================
__global__ __launch_bounds__(256) void gemm_xw(const float* __restrict__ x,
                                               const float* __restrict__ w,
                                               float* __restrict__ support,
                                               int N) {
    __shared__ float xs[32][D];  // 32 KB
    const int tid  = threadIdx.x;
    const int wave = tid >> 6;
    const int lane = tid & 63;
    const int row0 = blockIdx.x * 32;

    // cooperative load: 32 rows x 64 float4 = 2048 float4, 8 per thread
    for (int i = tid; i < 32 * 64; i += 256) {
        const int r  = i >> 6;
        const int c  = i & 63;
        int gr = row0 + r;
        if (gr >= N) gr = N - 1;  // clamp (harmless duplicate)
        ((float4*)xs[r])[c] = ((const float4*)(x + (size_t)gr * D))[c];
    }
    __syncthreads();

    float4 acc[8];
#pragma unroll
    for (int r = 0; r < 8; ++r) acc[r] = make_float4(0.f, 0.f, 0.f, 0.f);

#pragma unroll 4
    for (int k = 0; k < D; ++k) {
        const float4 wv = *(const float4*)(w + k * D + lane * 4);
#pragma unroll
        for (int r = 0; r < 8; ++r) {
            const float xk = xs[wave * 8 + r][k];  // wave-uniform -> LDS broadcast
            acc[r].x = fmaf(xk, wv.x, acc[r].x);
            acc[r].y = fmaf(xk, wv.y, acc[r].y);
            acc[r].z = fmaf(xk, wv.z, acc[r].z);
            acc[r].w = fmaf(xk, wv.w, acc[r].w);
        }
    }

#pragma unroll
    for (int r = 0; r < 8; ++r) {
        const int grow = row0 + wave * 8 + r;
        if (grow < N)
            *(float4*)(support + (size_t)grow * D + lane * 4) = acc[r];
    }
}

// ===========================================================================
// CSR build
// ===========================================================================
__global__ __launch_bounds__(256) void zero_ints(int* __restrict__ p, int n) {
    const int i = blockIdx.x * 256 + threadIdx.x;
    if (i < n) p[i] = 0;
}

__global__ __launch_bounds__(256) void hist_rows(const int* __restrict__ edge_row,
                                                 int* __restrict__ cnt, int E) {
    const int e = blockIdx.x * 256 + threadIdx.x;
    if (e < E) atomicAdd(&cnt[edge_row[e]], 1);
}

// block-local exclusive scan of cnt -> row_start (partial), block sums -> partial[]
__global__ __launch_bounds__(256) void scan_local(const int* __restrict__ cnt,
                                                  int* __restrict__ row_start,
                                                  int* __restrict__ partial, int N) {
    __shared__ int tmp[256];
    const int tid = threadIdx.x;
    const int i   = blockIdx.x * 256 + tid;
    const int v   = (i < N) ? cnt[i] : 0;
    tmp[tid] = v;
    __syncthreads();
#pragma unroll
    for (int off = 1; off < 256; off <<= 1) {
        const int t = (tid >= off) ? tmp[tid - off] : 0;
        __syncthreads();
        tmp[tid] += t;
        __syncthreads();
    }
    if (i < N) row_start[i] = tmp[tid] - v;  // exclusive
    if (tid == 255) partial[blockIdx.x] = tmp[255];
}

// single-block exclusive scan of partials (nblk <= 512)
__global__ __launch_bounds__(512) void scan_partials(int* __restrict__ partial, int nblk) {
    __shared__ int tmp[512];
    const int tid = threadIdx.x;
    const int v   = (tid < nblk) ? partial[tid] : 0;
    tmp[tid] = v;
    __syncthreads();
#pragma unroll
    for (int off = 1; off < 512; off <<= 1) {
        const int t = (tid >= off) ? tmp[tid - off] : 0;
        __syncthreads();
        tmp[tid] += t;
        __syncthreads();
    }
    if (tid < nblk) partial[tid] = tmp[tid] - v;
}

__global__ __launch_bounds__(256) void scan_finalize(int* __restrict__ row_start,
                                                     int* __restrict__ cursor,
                                                     const int* __restrict__ partial,
                                                     int N, int E) {
    const int i = blockIdx.x * 256 + threadIdx.x;
    if (i < N) {
        const int s = row_start[i] + partial[blockIdx.x];
        row_start[i] = s;
        cursor[i]    = s;
    }
    if (blockIdx.x == 0 && threadIdx.x == 0) row_start[N] = E;
}

__global__ __launch_bounds__(256) void fill_csr(const int* __restrict__ edge_row,
                                                const int* __restrict__ edge_col,
                                                const float* __restrict__ edge_val,
                                                int* __restrict__ cursor,
                                                int* __restrict__ scol,
                                                float* __restrict__ sval, int E) {
    const int e = blockIdx.x * 256 + threadIdx.x;
    if (e >= E) return;
    const int pos = atomicAdd(&cursor[edge_row[e]], 1);
    scol[pos] = edge_col[e];
    sval[pos] = edge_val[e];
}

// ===========================================================================
// Kernel 3: accumulate. One wave per output row; no output atomics.
// acc starts at bias. Edge metadata loaded coalesced 64-at-a-time, broadcast
// via shfl. Two edges in flight (acc0/acc1) for memory-level parallelism.
// ===========================================================================
__global__ __launch_bounds__(256) void accumulate(const float* __restrict__ support,
                                                  const int* __restrict__ row_start,
                                                  const int* __restrict__ scol,
                                                  const float* __restrict__ sval,
                                                  const float* __restrict__ bias,
                                                  float* __restrict__ out, int N) {
    const int row = blockIdx.x * 4 + (threadIdx.x >> 6);
    if (row >= N) return;
    const int lane = threadIdx.x & 63;

    const int s = row_start[row];
    const int e = row_start[row + 1];

    float4 acc0 = *(const float4*)(bias + lane * 4);
    float4 acc1 = make_float4(0.f, 0.f, 0.f, 0.f);

    for (int base = s; base < e; base += 64) {
        const int idx = base + lane;
        const int  c = (idx < e) ? scol[idx] : 0;
        const float v = (idx < e) ? sval[idx] : 0.f;
        const int n = min(64, e - base);
        int j = 0;
        for (; j + 1 < n; j += 2) {
            const int   c0 = __shfl(c, j);
            const float v0 = __shfl(v, j);
            const int   c1 = __shfl(c, j + 1);
            const float v1 = __shfl(v, j + 1);
            const float4 s0 = *(const float4*)(support + (size_t)c0 * D + lane * 4);
            const float4 s1 = *(const float4*)(support + (size_t)c1 * D + lane * 4);
            acc0.x = fmaf(v0, s0.x, acc0.x);
            acc0.y = fmaf(v0, s0.y, acc0.y);
            acc0.z = fmaf(v0, s0.z, acc0.z);
            acc0.w = fmaf(v0, s0.w, acc0.w);
            acc1.x = fmaf(v1, s1.x, acc1.x);
            acc1.y = fmaf(v1, s1.y, acc1.y);
            acc1.z = fmaf(v1, s1.z, acc1.z);
            acc1.w = fmaf(v1, s1.w, acc1.w);
        }
        if (j < n) {
            const int   c0 = __shfl(c, j);
            const float v0 = __shfl(v, j);
            const float4 s0 = *(const float4*)(support + (size_t)c0 * D + lane * 4);
            acc0.x = fmaf(v0, s0.x, acc0.x);
            acc0.y = fmaf(v0, s0.y, acc0.y);
            acc0.z = fmaf(v0, s0.z, acc0.z);
            acc0.w = fmaf(v0, s0.w, acc0.w);
        }
    }
    acc0.x += acc1.x; acc0.y += acc1.y; acc0.z += acc1.z; acc0.w += acc1.w;
    *(float4*)(out + (size_t)row * D + lane * 4) = acc0;
}

// ===========================================================================
// Fallback (if workspace too small): round-0 atomic path
// ===========================================================================
__global__ __launch_bounds__(256) void init_out(float* __restrict__ out,
                                                const float* __restrict__ bias, int N) {
    const int idx   = blockIdx.x * blockDim.x + threadIdx.x;
    const int total = N * (D / 4);
    if (idx >= total) return;
    const int d4 = idx & (D / 4 - 1);
    *(float4*)(out + (size_t)idx * 4) = *(const float4*)(bias + d4 * 4);
}

__global__ __launch_bounds__(256) void scatter_edges(const float* __restrict__ support,
                                                     const float* __restrict__ edge_val,
                                                     const int* __restrict__ edge_row,
                                                     const int* __restrict__ edge_col,
                                                     float* __restrict__ out, int E) {
    const int e = blockIdx.x * 4 + (threadIdx.x >> 6);
    if (e >= E) return;
    const int lane = threadIdx.x & 63;
    const int   row = edge_row[e];
    const int   col = edge_col[e];
    const float v   = edge_val[e];
    const float4 sv = *(const float4*)(support + (size_t)col * D + lane * 4);
    float* o = out + (size_t)row * D + lane * 4;
    atomicAdd(o + 0, v * sv.x);
    atomicAdd(o + 1, v * sv.y);
    atomicAdd(o + 2, v * sv.z);
    atomicAdd(o + 3, v * sv.w);
}

// ===========================================================================
extern "C" void kernel_launch(void* const* d_in, const int* in_sizes, int n_in,
                              void* d_out, int out_size, void* d_ws, size_t ws_size,
                              hipStream_t stream) {
    const float* x        = (const float*)d_in[0];
    const float* edge_val = (const float*)d_in[1];
    const float* weight   = (const float*)d_in[2];
    const float* bias     = (const float*)d_in[3];
    const int*   edge_row = (const int*)d_in[4];
    const int*   edge_col = (const int*)d_in[5];
    float*       out      = (float*)d_out;

    const int N = in_sizes[0] / D;   // 100000
    const int E = in_sizes[1];       // 3200000

    char* ws = (char*)d_ws;
    size_t off = 0;
    auto carve = [&](size_t bytes) -> char* {
        char* p = ws + off;
        off = (off + bytes + 255) & ~(size_t)255;
        return p;
    };

    const int nblk = (N + 255) / 256;   // 391

    float* support   = (float*)carve((size_t)N * D * sizeof(float));  // 102.4 MB
    int*   row_start = (int*)carve((size_t)(N + 1) * sizeof(int));
    int*   cursor    = (int*)carve((size_t)N * sizeof(int));          // also cnt
    int*   scol      = (int*)carve((size_t)E * sizeof(int));
    float* sval      = (float*)carve((size_t)E * sizeof(float));
    int*   partial   = (int*)carve((size_t)nblk * sizeof(int));

    const bool have_ws = (off <= ws_size);

    // 1) support = x @ W
    gemm_xw<<<(N + 31) / 32, 256, 0, stream>>>(x, weight, support, N);

    if (have_ws) {
        // 2) CSR build: hist -> scan -> fill
        zero_ints<<<nblk, 256, 0, stream>>>(cursor, N);
        hist_rows<<<(E + 255) / 256, 256, 0, stream>>>(edge_row, cursor, E);
        scan_local<<<nblk, 256, 0, stream>>>(cursor, row_start, partial, N);
        scan_partials<<<1, 512, 0, stream>>>(partial, nblk);
        scan_finalize<<<nblk, 256, 0, stream>>>(row_start, cursor, partial, N, E);
        fill_csr<<<(E + 255) / 256, 256, 0, stream>>>(edge_row, edge_col, edge_val,
                                                      cursor, scol, sval, E);
        // 3) gather-accumulate, bias folded in
        accumulate<<<(N + 3) / 4, 256, 0, stream>>>(support, row_start, scol, sval,
                                                    bias, out, N);
    } else {
        // fallback: atomic scatter
        init_out<<<(N * (D / 4) + 255) / 256, 256, 0, stream>>>(out, bias, N);
        scatter_edges<<<(E + 3) / 4, 256, 0, stream>>>(support, edge_val, edge_row,
                                                       edge_col, out, E);
    }
}

// Round 3
// 724.869 us; speedup vs baseline: 15.6515x; 1.3382x over previous
//
#include <hip/hip_runtime.h>

#define D 256  // D_IN == D_OUT == 256

typedef __attribute__((ext_vector_type(8))) short bf16x8;  // 8 bf16 in 4 VGPRs
typedef __attribute__((ext_vector_type(4))) float f32x4;

__device__ inline ushort f2bf_rne(float f) {  // fp32 -> bf16, round-to-nearest-even
    uint u = __builtin_bit_cast(uint, f);
    return (ushort)((u + 0x7FFFu + ((u >> 16) & 1u)) >> 16);
}

// ===========================================================================
// W transpose + bf16 convert: wt[n][k] = bf16(W[k][n]).  65536 elems, trivial.
// ===========================================================================
__global__ __launch_bounds__(256) void conv_wt(const float* __restrict__ w,
                                               ushort* __restrict__ wt) {
    const int idx = blockIdx.x * 256 + threadIdx.x;
    const int n = idx >> 8, k = idx & 255;
    wt[n * 256 + k] = f2bf_rne(w[k * 256 + n]);
}

// ===========================================================================
// support = bf16(x @ W) via MFMA 16x16x32 bf16.
// Block = 4 waves, BM=64 rows. A-tile staged fp32->bf16 into XOR-swizzled LDS
// (row stride 512B would be a 16-way bank conflict on ds_read_b128; the
// ^((r&7)<<4) swizzle reduces it to 2-way = free). B-frags read straight from
// wt (bf16, [n][k] row-major -> 16B contiguous per frag, L1/L2-hot 128 KB).
// C/D layout (m89-verified): col = lane&15, row = 4*(lane>>4) + reg.
// ===========================================================================
__global__ __launch_bounds__(256) void gemm_mfma(const float* __restrict__ x,
                                                 const ushort* __restrict__ wt,
                                                 ushort* __restrict__ sup,
                                                 int N) {
    __shared__ ushort As[64 * 256];  // 32 KB, XOR-swizzled
    const int tid = threadIdx.x;
    const int wv  = tid >> 6;
    const int ln  = tid & 63;
    const int row0 = blockIdx.x * 64;

    // stage 64x256 x-tile as bf16 (each iter: one float4 -> one 8B bf16 chunk)
    for (int i = tid; i < 64 * 64; i += 256) {
        const int r = i >> 6, c = i & 63;
        int gr = row0 + r;
        if (gr >= N) gr = N - 1;  // clamp: harmless duplicate
        const float4 xv = *(const float4*)(x + (size_t)gr * D + c * 4);
        ushort4 b;
        b.x = f2bf_rne(xv.x); b.y = f2bf_rne(xv.y);
        b.z = f2bf_rne(xv.z); b.w = f2bf_rne(xv.w);
        const int byte = (r * 512 + c * 8) ^ ((r & 7) << 4);
        *(ushort4*)((char*)As + byte) = b;
    }
    __syncthreads();

    f32x4 acc[16];
#pragma unroll
    for (int n = 0; n < 16; ++n) acc[n] = (f32x4){0.f, 0.f, 0.f, 0.f};

    const int arow = wv * 16 + (ln & 15);       // A row this lane feeds
    const int ksub = (ln >> 4) * 16;            // byte offset of this lane's k-group
    const ushort* wbase = wt + (ln & 15) * 256; // B col base (n-frag 0)

#pragma unroll
    for (int kk = 0; kk < 8; ++kk) {
        const int abyte = (arow * 512 + kk * 64 + ksub) ^ ((arow & 7) << 4);
        const bf16x8 af = *(const bf16x8*)((const char*)As + abyte);
        const ushort* wp = wbase + kk * 32 + (ln >> 4) * 8;
#pragma unroll
        for (int n = 0; n < 16; ++n) {
            const bf16x8 bf = *(const bf16x8*)(wp + n * 16 * 256);
            acc[n] = __builtin_amdgcn_mfma_f32_16x16x32_bf16(af, bf, acc[n], 0, 0, 0);
        }
    }

    const int crow = row0 + wv * 16 + (ln >> 4) * 4;
    const int ccol = ln & 15;
#pragma unroll
    for (int n = 0; n < 16; ++n) {
#pragma unroll
        for (int reg = 0; reg < 4; ++reg) {
            const int r = crow + reg;
            if (r < N) sup[(size_t)r * D + n * 16 + ccol] = f2bf_rne(acc[n][reg]);
        }
    }
}

// ===========================================================================
// CSR build
// ===========================================================================
__global__ __launch_bounds__(256) void zero_ints(int* __restrict__ p, int n) {
    const int i = blockIdx.x * 256 + threadIdx.x;
    if (i < n) p[i] = 0;
}

__global__ __launch_bounds__(256) void hist_rows(const int* __restrict__ edge_row,
                                                 int* __restrict__ cnt, int E) {
    const int e = blockIdx.x * 256 + threadIdx.x;
    if (e < E) atomicAdd(&cnt[edge_row[e]], 1);
}

__global__ __launch_bounds__(256) void scan_local(const int* __restrict__ cnt,
                                                  int* __restrict__ row_start,
                                                  int* __restrict__ partial, int N) {
    __shared__ int tmp[256];
    const int tid = threadIdx.x;
    const int i   = blockIdx.x * 256 + tid;
    const int v   = (i < N) ? cnt[i] : 0;
    tmp[tid] = v;
    __syncthreads();
#pragma unroll
    for (int off = 1; off < 256; off <<= 1) {
        const int t = (tid >= off) ? tmp[tid - off] : 0;
        __syncthreads();
        tmp[tid] += t;
        __syncthreads();
    }
    if (i < N) row_start[i] = tmp[tid] - v;
    if (tid == 255) partial[blockIdx.x] = tmp[255];
}

__global__ __launch_bounds__(512) void scan_partials(int* __restrict__ partial, int nblk) {
    __shared__ int tmp[512];
    const int tid = threadIdx.x;
    const int v   = (tid < nblk) ? partial[tid] : 0;
    tmp[tid] = v;
    __syncthreads();
#pragma unroll
    for (int off = 1; off < 512; off <<= 1) {
        const int t = (tid >= off) ? tmp[tid - off] : 0;
        __syncthreads();
        tmp[tid] += t;
        __syncthreads();
    }
    if (tid < nblk) partial[tid] = tmp[tid] - v;
}

__global__ __launch_bounds__(256) void scan_finalize(int* __restrict__ row_start,
                                                     int* __restrict__ cursor,
                                                     const int* __restrict__ partial,
                                                     int N, int E) {
    const int i = blockIdx.x * 256 + threadIdx.x;
    if (i < N) {
        const int s = row_start[i] + partial[blockIdx.x];
        row_start[i] = s;
        cursor[i]    = s;
    }
    if (blockIdx.x == 0 && threadIdx.x == 0) row_start[N] = E;
}

__global__ __launch_bounds__(256) void fill_csr(const int* __restrict__ edge_row,
                                                const int* __restrict__ edge_col,
                                                const float* __restrict__ edge_val,
                                                int* __restrict__ cursor,
                                                int* __restrict__ scol,
                                                float* __restrict__ sval, int E) {
    const int e = blockIdx.x * 256 + threadIdx.x;
    if (e >= E) return;
    const int pos = atomicAdd(&cursor[edge_row[e]], 1);
    scol[pos] = edge_col[e];
    sval[pos] = edge_val[e];
}

// ===========================================================================
// accumulate: one wave per output row, bf16 support gathers (8B/lane/edge),
// fp32 accumulation, bias folded in, 4 edges in flight for MLP.
// ===========================================================================
__device__ inline void fma_edge(float4& acc, const ushort* __restrict__ sup,
                                int c, float v, int lane) {
    const uint2 u = *(const uint2*)(sup + (size_t)c * D + lane * 4);
    const float f0 = __builtin_bit_cast(float, u.x << 16);
    const float f1 = __builtin_bit_cast(float, u.x & 0xFFFF0000u);
    const float f2 = __builtin_bit_cast(float, u.y << 16);
    const float f3 = __builtin_bit_cast(float, u.y & 0xFFFF0000u);
    acc.x = fmaf(v, f0, acc.x);
    acc.y = fmaf(v, f1, acc.y);
    acc.z = fmaf(v, f2, acc.z);
    acc.w = fmaf(v, f3, acc.w);
}

__global__ __launch_bounds__(256) void accumulate(const ushort* __restrict__ sup,
                                                  const int* __restrict__ row_start,
                                                  const int* __restrict__ scol,
                                                  const float* __restrict__ sval,
                                                  const float* __restrict__ bias,
                                                  float* __restrict__ out, int N) {
    const int row = blockIdx.x * 4 + (threadIdx.x >> 6);
    if (row >= N) return;
    const int lane = threadIdx.x & 63;

    const int s = row_start[row];
    const int e = row_start[row + 1];

    float4 a0 = *(const float4*)(bias + lane * 4);
    float4 a1 = make_float4(0.f, 0.f, 0.f, 0.f);
    float4 a2 = make_float4(0.f, 0.f, 0.f, 0.f);
    float4 a3 = make_float4(0.f, 0.f, 0.f, 0.f);

    for (int base = s; base < e; base += 64) {
        const int idx = base + lane;
        const int   c = (idx < e) ? scol[idx] : 0;
        const float v = (idx < e) ? sval[idx] : 0.f;
        const int n = min(64, e - base);
        int j = 0;
        for (; j + 3 < n; j += 4) {
            const int   c0 = __shfl(c, j),     c1 = __shfl(c, j + 1);
            const int   c2 = __shfl(c, j + 2), c3 = __shfl(c, j + 3);
            const float v0 = __shfl(v, j),     v1 = __shfl(v, j + 1);
            const float v2 = __shfl(v, j + 2), v3 = __shfl(v, j + 3);
            fma_edge(a0, sup, c0, v0, lane);
            fma_edge(a1, sup, c1, v1, lane);
            fma_edge(a2, sup, c2, v2, lane);
            fma_edge(a3, sup, c3, v3, lane);
        }
        for (; j < n; ++j) {
            const int   c0 = __shfl(c, j);
            const float v0 = __shfl(v, j);
            fma_edge(a0, sup, c0, v0, lane);
        }
    }
    a0.x += a1.x + a2.x + a3.x;
    a0.y += a1.y + a2.y + a3.y;
    a0.z += a1.z + a2.z + a3.z;
    a0.w += a1.w + a2.w + a3.w;
    *(float4*)(out + (size_t)row * D + lane * 4) = a0;
}

// ===========================================================================
// Fallback (workspace too small): atomic scatter path (bf16 support)
// ===========================================================================
__global__ __launch_bounds__(256) void init_out(float* __restrict__ out,
                                                const float* __restrict__ bias, int N) {
    const int idx   = blockIdx.x * blockDim.x + threadIdx.x;
    const int total = N * (D / 4);
    if (idx >= total) return;
    const int d4 = idx & (D / 4 - 1);
    *(float4*)(out + (size_t)idx * 4) = *(const float4*)(bias + d4 * 4);
}

__global__ __launch_bounds__(256) void scatter_edges(const ushort* __restrict__ sup,
                                                     const float* __restrict__ edge_val,
                                                     const int* __restrict__ edge_row,
                                                     const int* __restrict__ edge_col,
                                                     float* __restrict__ out, int E) {
    const int e = blockIdx.x * 4 + (threadIdx.x >> 6);
    if (e >= E) return;
    const int lane = threadIdx.x & 63;
    const int   row = edge_row[e];
    const int   col = edge_col[e];
    const float v   = edge_val[e];
    float4 m = make_float4(0.f, 0.f, 0.f, 0.f);
    fma_edge(m, sup, col, v, lane);
    float* o = out + (size_t)row * D + lane * 4;
    atomicAdd(o + 0, m.x);
    atomicAdd(o + 1, m.y);
    atomicAdd(o + 2, m.z);
    atomicAdd(o + 3, m.w);
}

// ===========================================================================
extern "C" void kernel_launch(void* const* d_in, const int* in_sizes, int n_in,
                              void* d_out, int out_size, void* d_ws, size_t ws_size,
                              hipStream_t stream) {
    const float* x        = (const float*)d_in[0];
    const float* edge_val = (const float*)d_in[1];
    const float* weight   = (const float*)d_in[2];
    const float* bias     = (const float*)d_in[3];
    const int*   edge_row = (const int*)d_in[4];
    const int*   edge_col = (const int*)d_in[5];
    float*       out      = (float*)d_out;

    const int N = in_sizes[0] / D;   // 100000
    const int E = in_sizes[1];       // 3200000

    char* ws = (char*)d_ws;
    size_t off = 0;
    auto carve = [&](size_t bytes) -> char* {
        char* p = ws + off;
        off = (off + bytes + 255) & ~(size_t)255;
        return p;
    };

    const int nblk = (N + 255) / 256;  // 391

    ushort* sup       = (ushort*)carve((size_t)N * D * sizeof(ushort));  // 51.2 MB
    ushort* wt        = (ushort*)carve((size_t)D * D * sizeof(ushort));  // 128 KB
    int*    row_start = (int*)carve((size_t)(N + 1) * sizeof(int));
    int*    cursor    = (int*)carve((size_t)N * sizeof(int));
    int*    scol      = (int*)carve((size_t)E * sizeof(int));
    float*  sval      = (float*)carve((size_t)E * sizeof(float));
    int*    partial   = (int*)carve((size_t)nblk * sizeof(int));

    const bool have_ws = (off <= ws_size);

    // 1) W -> wt (bf16, transposed), then support = bf16(x @ W) via MFMA
    conv_wt<<<(D * D) / 256, 256, 0, stream>>>(weight, wt);
    gemm_mfma<<<(N + 63) / 64, 256, 0, stream>>>(x, wt, sup, N);

    if (have_ws) {
        // 2) CSR build
        zero_ints<<<nblk, 256, 0, stream>>>(cursor, N);
        hist_rows<<<(E + 255) / 256, 256, 0, stream>>>(edge_row, cursor, E);
        scan_local<<<nblk, 256, 0, stream>>>(cursor, row_start, partial, N);
        scan_partials<<<1, 512, 0, stream>>>(partial, nblk);
        scan_finalize<<<nblk, 256, 0, stream>>>(row_start, cursor, partial, N, E);
        fill_csr<<<(E + 255) / 256, 256, 0, stream>>>(edge_row, edge_col, edge_val,
                                                      cursor, scol, sval, E);
        // 3) gather-accumulate
        accumulate<<<(N + 3) / 4, 256, 0, stream>>>(sup, row_start, scol, sval,
                                                    bias, out, N);
    } else {
        init_out<<<(N * (D / 4) + 255) / 256, 256, 0, stream>>>(out, bias, N);
        scatter_edges<<<(E + 3) / 4, 256, 0, stream>>>(sup, edge_val, edge_row,
                                                       edge_col, out, E);
    }
}